// Round 1
// baseline (37774.905 us; speedup 1.0000x reference)
//
#include <hip/hip_runtime.h>
#include <hip/hip_cooperative_groups.h>
#include <math.h>

namespace cg = cooperative_groups;

#define B_ 128
#define T_ 512
#define I_ 128
#define H_ 1024
#define G4_ 4096
#define KE_ 1152  // I_ + H_

typedef short short8 __attribute__((ext_vector_type(8)));
typedef float f32x4 __attribute__((ext_vector_type(4)));

__device__ __forceinline__ float bf2f(unsigned short u){
  unsigned int x = ((unsigned int)u)<<16; float f; __builtin_memcpy(&f,&x,4); return f;
}
__device__ __forceinline__ unsigned short f2bf(float f){
  unsigned int x; __builtin_memcpy(&x,&f,4);
  x += 0x7fffu + ((x>>16)&1u);
  return (unsigned short)(x>>16);
}
__device__ __forceinline__ float sigm(float x){ return 1.f/(1.f+__expf(-x)); }
__device__ __forceinline__ float tanh_(float x){ return 1.f - 2.f/(1.f+__expf(2.f*x)); }

// ---------------- prepass kernels ----------------

__global__ void k_f32_to_bf16(const float* __restrict__ src, unsigned short* __restrict__ dst, int n){
  int i = blockIdx.x*256 + threadIdx.x;
  if(i < n) dst[i] = f2bf(src[i]);
}

// out[n][k] = k<128 ? Wih[n][k] : Whh[n][k-128]   (bf16, row-major [4096][1152])
__global__ void k_build_wcat(const float* __restrict__ Wih, const float* __restrict__ Whh,
                             unsigned short* __restrict__ out){
  int n = blockIdx.y;
  int k = blockIdx.x*256 + threadIdx.x;
  if(k < KE_){
    float v = (k < I_) ? Wih[n*I_ + k] : Whh[n*H_ + (k - I_)];
    out[n*KE_ + k] = f2bf(v);
  }
}

// Weff[n][k] = dec_Whh[n][k] + sum_j dec_Wih[n][j]*lin_W[j][k]   (bf16 [4096][1024])
__global__ void k_build_weff(const float* __restrict__ Wih, const float* __restrict__ Whh,
                             const float* __restrict__ linW, unsigned short* __restrict__ out){
  int n = blockIdx.y;
  int k = blockIdx.x*256 + threadIdx.x;  // < 1024
  float acc = Whh[n*H_ + k];
  for(int j=0;j<I_;j++) acc += Wih[n*I_ + j] * linW[j*H_ + k];
  out[n*H_ + k] = f2bf(acc);
}

__global__ void k_build_bias(const float* __restrict__ ebih, const float* __restrict__ ebhh,
                             const float* __restrict__ dbih, const float* __restrict__ dbhh,
                             const float* __restrict__ dWih, const float* __restrict__ linb,
                             float* __restrict__ encb, float* __restrict__ decb, float* __restrict__ decbeff){
  int n = blockIdx.x*256 + threadIdx.x;  // < 4096
  encb[n] = ebih[n] + ebhh[n];
  float db = dbih[n] + dbhh[n];
  decb[n] = db;
  float acc = db;
  for(int j=0;j<I_;j++) acc += linb[j]*dWih[n*I_ + j];
  decbeff[n] = acc;
}

__global__ void k_init_h(unsigned short* __restrict__ h0){
  int i = blockIdx.x*256 + threadIdx.x;  // < B_*H_
  if(i < B_*H_) h0[i] = 0;
}

// ---------------- persistent-kernel device helpers ----------------

__device__ __forceinline__ void mfma_step(const unsigned short* __restrict__ Wp,
    const int* __restrict__ wrow, int kb, short8 a0, short8 a1, f32x4 acc[2][4])
{
  #pragma unroll
  for(int g=0; g<4; ++g){
    const short8 bf = *(const short8*)(Wp + wrow[g] + kb);
    acc[0][g] = __builtin_amdgcn_mfma_f32_16x16x32_bf16(a0, bf, acc[0][g], 0,0,0);
    acc[1][g] = __builtin_amdgcn_mfma_f32_16x16x32_bf16(a1, bf, acc[1][g], 0,0,0);
  }
}

// GEMM with A = [x(128) | h(1024)], K = 1152
template<int NK>
__device__ __forceinline__ void gemm_x(const unsigned short* __restrict__ Wp,
    const int* __restrict__ wrow,
    const unsigned short* __restrict__ xp0, const unsigned short* __restrict__ xp1,
    const unsigned short* __restrict__ hp0, const unsigned short* __restrict__ hp1,
    f32x4 acc[2][4])
{
  #pragma unroll
  for(int ks=0; ks<4; ++ks){          // x part: kb = 0..127
    const int kb = ks*32;
    mfma_step(Wp, wrow, kb, *(const short8*)(xp0 + kb), *(const short8*)(xp1 + kb), acc);
  }
  #pragma unroll 4
  for(int ks=4; ks<NK; ++ks){         // h part
    const int kb = ks*32;
    mfma_step(Wp, wrow, kb, *(const short8*)(hp0 + kb - I_), *(const short8*)(hp1 + kb - I_), acc);
  }
}

// GEMM with A = h only, K = 1024
template<int NK>
__device__ __forceinline__ void gemm_h(const unsigned short* __restrict__ Wp,
    const int* __restrict__ wrow,
    const unsigned short* __restrict__ hp0, const unsigned short* __restrict__ hp1,
    f32x4 acc[2][4])
{
  #pragma unroll 4
  for(int ks=0; ks<NK; ++ks){
    const int kb = ks*32;
    mfma_step(Wp, wrow, kb, *(const short8*)(hp0 + kb), *(const short8*)(hp1 + kb), acc);
  }
}

// out tile = h[rb..rb+16) @ lin_W^T[cb..cb+16) + lin_b, K=1024 split over 4 waves
__device__ __forceinline__ void proj_tile(const unsigned short* __restrict__ hsrc,
    const unsigned short* __restrict__ linwbf, const float* __restrict__ linb,
    float* __restrict__ dout, int b, int w, int l, int tcol, f32x4* red)
{
  const int lr = l & 15, lq = l >> 4;
  const int rb = (b >> 3) * 16, cb = (b & 7) * 16;
  f32x4 aco = (f32x4){0.f,0.f,0.f,0.f};
  #pragma unroll
  for(int ki=0; ki<8; ++ki){
    const int kb = (w*8 + ki)*32;
    short8 af = *(const short8*)(hsrc  + (rb+lr)*H_ + kb + lq*8);
    short8 bf = *(const short8*)(linwbf + (cb+lr)*H_ + kb + lq*8);
    aco = __builtin_amdgcn_mfma_f32_16x16x32_bf16(af, bf, aco, 0,0,0);
  }
  red[w*64 + l] = aco;
  __syncthreads();
  if(w == 0){
    f32x4 s = red[l] + red[64+l] + red[128+l] + red[192+l];
    #pragma unroll
    for(int r=0;r<4;r++)
      dout[(long)(rb + lq*4 + r)*(T_*I_) + (long)tcol*I_ + cb + lr] = s[r] + linb[cb + lr];
  }
  __syncthreads();
}

// ---------------- the persistent kernel: all 1024 steps ----------------
// 64 blocks x 256 threads, cooperative. Block b owns h-cols [16b,16b+16) and the
// 4 matching 16-col gate strips. Wave w owns rows [32w,32w+32). c and (own) h
// state live in registers; h is exchanged through global bf16 double buffers
// with one grid.sync per step.
__global__ __launch_bounds__(256) void k_persist(
    const unsigned short* __restrict__ encW,   // [4096][1152] bf16
    const unsigned short* __restrict__ decW,   // [4096][1152] bf16
    const unsigned short* __restrict__ weffW,  // [4096][1024] bf16
    const unsigned short* __restrict__ xbf,    // [B][T][I] bf16
    unsigned short* __restrict__ h0buf,        // [B][H] bf16
    unsigned short* __restrict__ h1buf,        // [B][H] bf16
    const float* __restrict__ bias_enc,        // [4096]
    const float* __restrict__ bias_tf1,        // [4096]
    const float* __restrict__ bias_tf0,        // [4096]
    const int* __restrict__ lengths,           // [B]
    const int* __restrict__ tfmask,            // [T]
    const unsigned short* __restrict__ linwbf, // [128][1024] bf16
    const float* __restrict__ linb,            // [128]
    float* __restrict__ dout)
{
  cg::grid_group grid = cg::this_grid();

  const int b   = blockIdx.x;      // 0..63
  const int tid = threadIdx.x;
  const int w   = tid >> 6;        // wave 0..3
  const int l   = tid & 63;
  const int lr  = l & 15;
  const int lq  = l >> 4;
  const int hc0 = b * 16;
  const int hc  = hc0 + lr;
  const int am0 = w*32 + lr;       // A rows for rowtile 0/1
  const int am1 = am0 + 16;

  __shared__ f32x4 red[4*64];

  int wrowA[4], wrowB[4];          // B-frag row bases (elements), K=1152 / K=1024
  #pragma unroll
  for(int g=0; g<4; ++g){
    wrowA[g] = (g*H_ + hc0 + lr)*KE_ + lq*8;
    wrowB[g] = (g*H_ + hc0 + lr)*H_  + lq*8;
  }

  // per-thread recurrent state: this thread owns cells (mm, hc),
  // mm = w*32 + rt*16 + lq*4 + r  — fixed for the whole run.
  float creg[2][4], hreg[2][4];
  int lenr[2][4];
  #pragma unroll
  for(int rt=0; rt<2; ++rt)
    #pragma unroll
    for(int r=0; r<4; ++r){
      creg[rt][r] = 0.f; hreg[rt][r] = 0.f;
      lenr[rt][r] = lengths[w*32 + rt*16 + lq*4 + r];
    }

  for(int s=0; s<2*T_; ++s){
    const int dec = s >> 9;                    // 0 = encoder, 1 = decoder
    const int t   = s & (T_-1);
    const unsigned short* hread = (s & 1) ? h1buf : h0buf;
    unsigned short* hwrite      = (s & 1) ? h0buf : h1buf;

    f32x4 acc[2][4];
    #pragma unroll
    for(int rt=0; rt<2; ++rt)
      #pragma unroll
      for(int g=0; g<4; ++g) acc[rt][g] = (f32x4){0.f,0.f,0.f,0.f};

    const unsigned short* hp0 = hread + am0*H_ + lq*8;
    const unsigned short* hp1 = hread + am1*H_ + lq*8;
    const float* bias;

    if(dec == 0){
      bias = bias_enc;
      const unsigned short* xp0 = xbf + (long)am0*(T_*I_) + (long)t*I_ + lq*8;
      const unsigned short* xp1 = xbf + (long)am1*(T_*I_) + (long)t*I_ + lq*8;
      gemm_x<KE_/32>(encW, wrowA, xp0, xp1, hp0, hp1, acc);
    } else {
      const int tf = (t == 0) ? 1 : tfmask[t-1];
      if(tf){
        bias = bias_tf1;
        const int xt = (t == 0) ? (T_-1) : (t-1);
        const unsigned short* xp0 = xbf + (long)am0*(T_*I_) + (long)xt*I_ + lq*8;
        const unsigned short* xp1 = xbf + (long)am1*(T_*I_) + (long)xt*I_ + lq*8;
        gemm_x<KE_/32>(decW, wrowA, xp0, xp1, hp0, hp1, acc);
      } else {
        bias = bias_tf0;
        gemm_h<H_/32>(weffW, wrowB, hp0, hp1, acc);
      }
    }

    // epilogue: activations + c/h update (c,h-own in registers)
    const float bI = bias[hc], bF = bias[H_+hc], bG = bias[2*H_+hc], bO = bias[3*H_+hc];
    #pragma unroll
    for(int rt=0; rt<2; ++rt){
      #pragma unroll
      for(int r=0; r<4; ++r){
        const int mm = w*32 + rt*16 + lq*4 + r;
        const float gi = acc[rt][0][r] + bI;
        const float gf = acc[rt][1][r] + bF;
        const float gg = acc[rt][2][r] + bG;
        const float go = acc[rt][3][r] + bO;
        const float i_ = sigm(gi), f_ = sigm(gf), g_ = tanh_(gg), o_ = sigm(go);
        const float cp = creg[rt][r];
        const float c2 = f_*cp + i_*g_;
        const float h2 = o_ * tanh_(c2);
        if(dec == 0){
          const int vm = (t < lenr[rt][r]) ? 1 : 0;
          const float hn = vm ? h2 : hreg[rt][r];
          creg[rt][r] = vm ? c2 : cp;
          hreg[rt][r] = hn;
          hwrite[mm*H_ + hc] = f2bf(hn);
          dout[(long)(B_*T_*I_) + (long)mm*(T_*H_) + (long)t*H_ + hc] = vm ? h2 : 0.f;
        } else {
          creg[rt][r] = c2;
          hreg[rt][r] = h2;
          hwrite[mm*H_ + hc] = f2bf(h2);
        }
      }
    }

    // decoder: out_{t-1} = h_read @ lin_W^T + lin_b  (K split over 4 waves)
    if(dec && t > 0) proj_tile(hread, linwbf, linb, dout, b, w, l, t-1, red);

    grid.sync();
  }

  // final projection out_{T-1} from final decoder h (in h0buf after step 1023)
  proj_tile(h0buf, linwbf, linb, dout, b, w, l, T_-1, red);
}

// ---------------- host ----------------

extern "C" void kernel_launch(void* const* d_in, const int* in_sizes, int n_in,
                              void* d_out, int out_size, void* d_ws, size_t ws_size,
                              hipStream_t stream) {
  const float* x       = (const float*)d_in[0];
  const float* eWih    = (const float*)d_in[1];
  const float* eWhh    = (const float*)d_in[2];
  const float* ebih    = (const float*)d_in[3];
  const float* ebhh    = (const float*)d_in[4];
  const float* dWih    = (const float*)d_in[5];
  const float* dWhh    = (const float*)d_in[6];
  const float* dbih    = (const float*)d_in[7];
  const float* dbhh    = (const float*)d_in[8];
  const float* linW    = (const float*)d_in[9];
  const float* linb    = (const float*)d_in[10];
  const int*   lengths = (const int*)d_in[11];
  const int*   tfmask  = (const int*)d_in[12];
  float* dout = (float*)d_out;

  char* ws = (char*)d_ws;
  size_t off = 0;
  auto alloc = [&](size_t bytes)->char*{ char* p = ws + off; off = (off + bytes + 255) & ~(size_t)255; return p; };
  unsigned short* xbf   = (unsigned short*)alloc((size_t)B_*T_*I_*2);   // 16 MB
  unsigned short* encW  = (unsigned short*)alloc((size_t)G4_*KE_*2);    // 9.4 MB
  unsigned short* decW  = (unsigned short*)alloc((size_t)G4_*KE_*2);    // 9.4 MB
  unsigned short* weff  = (unsigned short*)alloc((size_t)G4_*H_*2);     // 8.4 MB
  unsigned short* linwb = (unsigned short*)alloc((size_t)I_*H_*2);      // 256 KB
  unsigned short* h0    = (unsigned short*)alloc((size_t)B_*H_*2);
  unsigned short* h1    = (unsigned short*)alloc((size_t)B_*H_*2);
  float*          encb  = (float*)alloc((size_t)G4_*4);
  float*          decb  = (float*)alloc((size_t)G4_*4);
  float*          decbe = (float*)alloc((size_t)G4_*4);

  // prepass
  k_f32_to_bf16<<<dim3((B_*T_*I_+255)/256), dim3(256), 0, stream>>>(x, xbf, B_*T_*I_);
  k_f32_to_bf16<<<dim3((I_*H_+255)/256),   dim3(256), 0, stream>>>(linW, linwb, I_*H_);
  k_build_wcat<<<dim3(5, G4_), dim3(256), 0, stream>>>(eWih, eWhh, encW);
  k_build_wcat<<<dim3(5, G4_), dim3(256), 0, stream>>>(dWih, dWhh, decW);
  k_build_weff<<<dim3(4, G4_), dim3(256), 0, stream>>>(dWih, dWhh, linW, weff);
  k_build_bias<<<dim3(16), dim3(256), 0, stream>>>(ebih, ebhh, dbih, dbhh, dWih, linb, encb, decb, decbe);
  k_init_h<<<dim3((B_*H_+255)/256), dim3(256), 0, stream>>>(h0);

  // all 1024 recurrent steps in one persistent cooperative kernel
  void* kargs[] = {
    (void*)&encW, (void*)&decW, (void*)&weff, (void*)&xbf,
    (void*)&h0, (void*)&h1,
    (void*)&encb, (void*)&decb, (void*)&decbe,
    (void*)&lengths, (void*)&tfmask,
    (void*)&linwb, (void*)&linb, (void*)&dout
  };
  hipLaunchCooperativeKernel((void*)k_persist, dim3(64), dim3(256), kargs, 0, stream);
}